// Round 7
// baseline (672.719 us; speedup 1.0000x reference)
//
#include <hip/hip_runtime.h>
#include <hip/hip_bf16.h>
#include <math.h>

// GraphMAE: 3x GCNConv(relu) encoder -> 3-layer MLP decoder -> masked MSE.
// bf16 activation storage, f32 compute, MFMA bf16 matmuls.
// Round 7: CSR fill partitions bound to PHYSICAL XCDs via HW_REG_XCC_ID +
// per-partition chunk queues (work stealing). Writers of each csr line are
// XCD-local -> dirty lines written back once.
// Outputs: d_out[0] = loss, d_out[1..N*128] = z (f32).

#define DD 128

typedef unsigned short ushort_t;
typedef unsigned int uint_t;
typedef __attribute__((ext_vector_type(8))) short short8;
typedef __attribute__((ext_vector_type(4))) float f32x4;

__device__ __forceinline__ ushort_t f2bf(float f) {
  union { float f; uint_t u; } v; v.f = f;
  uint_t r = v.u + 0x7fff + ((v.u >> 16) & 1);
  return (ushort_t)(r >> 16);
}
__device__ __forceinline__ float u2f(uint_t u) {
  union { uint_t u; float f; } v; v.u = u;
  return v.f;
}

// ---------------- dtype detection (edge_index: i64 vs i32; mask: i32 vs u8) ---
__global__ void detect_kernel(const void* edge, const void* mask,
                              long long E, int N, int* flags) {
  __shared__ int bad_e, bad_m;
  if (threadIdx.x == 0) { bad_e = 0; bad_m = 0; }
  __syncthreads();
  const long long* e64 = (const long long*)edge;
  long long step = E / 1024; if (step < 1) step = 1;
  for (int i = threadIdx.x; i < 1024; i += blockDim.x) {
    long long idx = (long long)i * step;
    if (idx < E) {
      long long v = e64[idx];
      if (v < 0 || v >= N) atomicAdd(&bad_e, 1);
    }
  }
  const int* m32 = (const int*)mask;
  int nw = N / 4;
  for (int i = threadIdx.x; i < nw; i += blockDim.x) {
    int v = m32[i];
    if (v != 0 && v != 1) atomicAdd(&bad_m, 1);
  }
  __syncthreads();
  if (threadIdx.x == 0) {
    flags[0] = (bad_e == 0) ? 1 : 0;
    flags[1] = (bad_m == 0) ? 1 : 0;
  }
}

__device__ __forceinline__ int load_mask(const void* p, int i, int is32) {
  if (is32) return ((const int*)p)[i];
  return (int)((const unsigned char*)p)[i];
}

// ---------------- edge convert to int32 + degree count (fused) --------------
__global__ void cvt_kernel(const void* edge, long long E, int* s32, int* d32,
                           int* deg, const int* flags) {
  int is64 = flags[0];
  long long i = blockIdx.x * (long long)blockDim.x + threadIdx.x;
  long long stride = (long long)gridDim.x * blockDim.x;
  for (; i < E; i += stride) {
    int s, d;
    if (is64) {
      s = (int)((const long long*)edge)[i];
      d = (int)((const long long*)edge)[E + i];
    } else {
      s = ((const int*)edge)[i];
      d = ((const int*)edge)[E + i];
    }
    s32[i] = s;
    d32[i] = d;
    atomicAdd(&deg[d], 1);
  }
}

__global__ void dinv_kernel(const int* deg, float* dinv, int N, int Npad) {
  int i = blockIdx.x * blockDim.x + threadIdx.x;
  if (i < Npad) dinv[i] = (i < N) ? rsqrtf((float)deg[i] + 1.0f) : 0.f;
}

// ---------------- exclusive scan (3-pass) ----------------
__global__ void scan1_kernel(const int* cnt, int* row_excl, int* blocksums, int N) {
  __shared__ int s[1024];
  int t = threadIdx.x, g = blockIdx.x * 1024 + t;
  int v = (g < N) ? cnt[g] : 0;
  s[t] = v;
  __syncthreads();
  for (int off = 1; off < 1024; off <<= 1) {
    int add = (t >= off) ? s[t - off] : 0;
    __syncthreads();
    s[t] += add;
    __syncthreads();
  }
  if (g < N) row_excl[g] = s[t] - v;
  if (t == 1023) blocksums[blockIdx.x] = s[1023];
}

__global__ void scan2_kernel(int* blocksums, int nb, int* row_ptr, int N) {
  if (threadIdx.x == 0 && blockIdx.x == 0) {
    int run = 0;
    for (int b = 0; b < nb; ++b) { int t = blocksums[b]; blocksums[b] = run; run += t; }
    row_ptr[N] = run;
  }
}

__global__ void scan3_kernel(int* row_ptr, const int* blocksums, int* cursor, int N) {
  int g = blockIdx.x * 1024 + threadIdx.x;
  if (g < N) {
    int v = row_ptr[g] + blocksums[blockIdx.x];
    row_ptr[g] = v;
    cursor[g] = v;
  }
}

// ---------------- CSR fill: partitions bound to physical XCDs ---------------
// Each block reads its real XCD id (HW_REG_XCC_ID, HW-verified on gfx950) and
// drains the chunk queue of the dst-range partition bound to that XCD first,
// then steals from other queues. Correct for ANY block->XCD mapping; locality
// is best-effort. All writers of partition p's csr window sit on XCD p, so
// its dirty lines are written back once.
#define FILL_CHUNK 8192
__global__ void fillx_kernel(const int* __restrict__ s32, const int* __restrict__ d32,
                             long long E, int* cursor, int* csr_src, int N,
                             int* qnext) {
  unsigned xcc;
  asm("s_getreg_b32 %0, hwreg(HW_REG_XCC_ID)" : "=s"(xcc));
  int mypart = (int)(xcc & 7u);
  int nchunks = (int)((E + FILL_CHUNK - 1) / FILL_CHUNK);
  __shared__ int sc;
  for (int pi = 0; pi < 8; ++pi) {
    int p = (mypart + pi) & 7;
    int lo = (int)(((long long)N * p) >> 3);
    int hi = (int)(((long long)N * (p + 1)) >> 3);
    while (true) {
      __syncthreads();
      if (threadIdx.x == 0) sc = atomicAdd(&qnext[p], 1);
      __syncthreads();
      int c = sc;
      if (c >= nchunks) break;
      long long base = (long long)c * FILL_CHUNK;
      long long end = base + FILL_CHUNK;
      if (end > E) end = E;
      for (long long i = base + threadIdx.x; i < end; i += blockDim.x) {
        int d = d32[i];
        if (d >= lo && d < hi) {
          int pos = atomicAdd(&cursor[d], 1);
          csr_src[pos] = s32[i];
        }
      }
    }
  }
}

// ---------------- cast x -> bf16 (pad rows zeroed) ----------------
__global__ void castx_kernel(const float* __restrict__ x, ushort_t* __restrict__ xb,
                             long long nvalid, long long ntotal) {
  long long i = ((long long)blockIdx.x * blockDim.x + threadIdx.x) * 8;
  if (i >= ntotal) return;
  ushort_t o[8];
  if (i < nvalid) {
    float4 a = *(const float4*)(x + i);
    float4 b = *(const float4*)(x + i + 4);
    o[0] = f2bf(a.x); o[1] = f2bf(a.y); o[2] = f2bf(a.z); o[3] = f2bf(a.w);
    o[4] = f2bf(b.x); o[5] = f2bf(b.y); o[6] = f2bf(b.z); o[7] = f2bf(b.w);
  } else {
#pragma unroll
    for (int j = 0; j < 8; ++j) o[j] = 0;
  }
  *(short8*)(xb + i) = *(short8*)o;
}

// ---------------- transpose+cast weights: W[k][n] f32 -> WT[n][k] bf16 ------
struct WPtrs { const float* w[6]; };
__global__ void transw_kernel(WPtrs p, ushort_t* wt) {
  int wi = blockIdx.x;
  const float* W = p.w[wi];
  ushort_t* dst = wt + wi * 16384;
  for (int i = threadIdx.x; i < 16384; i += blockDim.x) {
    int k = i >> 7, n = i & 127;
    dst[n * 128 + k] = f2bf(W[i]);
  }
}

// ---------------- mask compaction (order-free) ----------------
__global__ void compact_kernel(const void* mask, const int* flags, int N,
                               int* cnt, int* midx) {
  int i = blockIdx.x * blockDim.x + threadIdx.x;
  if (i < N && load_mask(mask, i, flags[1])) {
    int p = atomicAdd(cnt, 1);
    midx[p] = i;
  }
}

// ---------------- MFMA matmul: out[rows][128] = A[rows][128] @ W ------------
__launch_bounds__(256, 4)
__global__ void mm_kernel(const ushort_t* __restrict__ A, const ushort_t* __restrict__ WT,
                          const float* __restrict__ bias, ushort_t* __restrict__ outb,
                          float* __restrict__ outf, int do_relu, int nrows,
                          const int* __restrict__ gidx, const int* __restrict__ gM,
                          const float* __restrict__ scale) {
  int limit = nrows;
  if (gM) limit = *gM;
  if ((long long)blockIdx.x * 64 >= limit) return;

  __shared__ __align__(16) char lds[32768];
  int tid = threadIdx.x;
  for (int cid = tid; cid < 2048; cid += 256) {
    int n = cid >> 4, kc = cid & 15;
    int dst = n * 256 + ((kc * 16) ^ ((n & 7) << 4));
    *(float4*)(lds + dst) = *(const float4*)(WT + n * 128 + kc * 8);
  }
  __syncthreads();

  int w = tid >> 6, l = tid & 63;
  long long R0 = (long long)blockIdx.x * 64 + w * 16;
  f32x4 acc[8];
#pragma unroll
  for (int c = 0; c < 8; ++c) acc[c] = (f32x4){0.f, 0.f, 0.f, 0.f};

  int r_log = (int)R0 + (l & 15);
  long long r_phys = r_log;
  if (gidx) r_phys = (r_log < limit) ? (long long)gidx[r_log] : 0;
  const ushort_t* arow = A + r_phys * 128;
#pragma unroll
  for (int ks = 0; ks < 4; ++ks) {
    short8 a = *(const short8*)(arow + ks * 32 + ((l >> 4) << 3));
#pragma unroll
    for (int c = 0; c < 8; ++c) {
      int nn = c * 16 + (l & 15);
      int kb = ks * 64 + ((l >> 4) << 4);
      short8 b = *(const short8*)(lds + nn * 256 + (kb ^ ((nn & 7) << 4)));
      acc[c] = __builtin_amdgcn_mfma_f32_16x16x32_bf16(a, b, acc[c], 0, 0, 0);
    }
  }

  int store_limit = gM ? limit : nrows;
  long long gr0 = R0 + ((l >> 4) << 2);
  float sc[4] = {1.f, 1.f, 1.f, 1.f};
  if (scale) {
#pragma unroll
    for (int r = 0; r < 4; ++r)
      sc[r] = (gr0 + r < store_limit) ? scale[gr0 + r] : 0.f;
  }
#pragma unroll
  for (int c = 0; c < 8; ++c) {
    int col = c * 16 + (l & 15);
    float bia = bias ? bias[col] : 0.f;
#pragma unroll
    for (int r = 0; r < 4; ++r) {
      if (gr0 + r < store_limit) {
        float v = acc[c][r] * sc[r] + bia;
        if (do_relu) v = fmaxf(v, 0.f);
        long long idx = (gr0 + r) * 128 + col;
        if (outb) outb[idx] = f2bf(v);
        if (outf) outf[idx] = v;
      }
    }
  }
}

// ---------------- GCN aggregation (wave/node; ht rows are dinv-premultiplied)
__global__ void agg_kernel(const ushort_t* __restrict__ ht, const float* __restrict__ dinv,
                           const int* __restrict__ rp, const int* __restrict__ csr,
                           const float* __restrict__ bias, ushort_t* __restrict__ outb,
                           float* __restrict__ zout, int N) {
  int v = blockIdx.x * 4 + (threadIdx.x >> 6);
  if (v >= N) return;
  int l = threadIdx.x & 63;
  int off = l * 2;
  int e0 = rp[v], e1 = rp[v + 1];

  float ax0 = 0.f, ax1 = 0.f, ax2 = 0.f, ax3 = 0.f;
  float ay0 = 0.f, ay1 = 0.f, ay2 = 0.f, ay3 = 0.f;

  auto gather1 = [&](int idx, bool act, float& axc, float& ayc) {
    int s = csr[idx];
    uint_t hv = *(const uint_t*)(ht + (size_t)s * 128 + off);
    hv = act ? hv : 0u;
    axc += u2f(hv << 16);
    ayc += u2f(hv & 0xffff0000u);
  };

  int e = e0;
  int deg = e1 - e0;
  int nh = (4 - (e0 & 3)) & 3;
  if (nh > deg) nh = deg;
  if (nh) {
    int last = e0 + nh - 1;
    gather1(e0, true, ax0, ay0);
    gather1(min(e0 + 1, last), nh > 1, ax1, ay1);
    gather1(min(e0 + 2, last), nh > 2, ax2, ay2);
    e += nh;
  }
#pragma unroll 2
  for (; e + 4 <= e1; e += 4) {
    int4 s4 = *(const int4*)(csr + e);
    uint_t h0 = *(const uint_t*)(ht + (size_t)s4.x * 128 + off);
    uint_t h1 = *(const uint_t*)(ht + (size_t)s4.y * 128 + off);
    uint_t h2 = *(const uint_t*)(ht + (size_t)s4.z * 128 + off);
    uint_t h3 = *(const uint_t*)(ht + (size_t)s4.w * 128 + off);
    ax0 += u2f(h0 << 16); ay0 += u2f(h0 & 0xffff0000u);
    ax1 += u2f(h1 << 16); ay1 += u2f(h1 & 0xffff0000u);
    ax2 += u2f(h2 << 16); ay2 += u2f(h2 & 0xffff0000u);
    ax3 += u2f(h3 << 16); ay3 += u2f(h3 & 0xffff0000u);
  }
  if (e < e1) {
    int last = e1 - 1;
    gather1(e, true, ax0, ay0);
    gather1(min(e + 1, last), e + 1 < e1, ax1, ay1);
    gather1(min(e + 2, last), e + 2 < e1, ax2, ay2);
  }

  float dv = dinv[v];
  uint_t sv = *(const uint_t*)(ht + (size_t)v * 128 + off);
  float ax = ((ax0 + ax1) + (ax2 + ax3)) + u2f(sv << 16);
  float ay = ((ay0 + ay1) + (ay2 + ay3)) + u2f(sv & 0xffff0000u);
  float vx = fmaxf(dv * ax + bias[off], 0.f);
  float vy = fmaxf(dv * ay + bias[off + 1], 0.f);
  uint_t packed = (uint_t)f2bf(vx) | ((uint_t)f2bf(vy) << 16);
  *(uint_t*)(outb + (size_t)v * 128 + off) = packed;
  if (zout) {
    *(float2*)(zout + (size_t)v * 128 + off) = make_float2(vx, vy);
  }
}

// ---------------- loss over compact masked rows ----------------
__global__ void loss_kernel(const float* __restrict__ r, const float* __restrict__ x,
                            const int* __restrict__ midx, const int* __restrict__ gM,
                            float* accum) {
  int M = *gM;
  long long total = (long long)M * 128;
  long long g = blockIdx.x * (long long)blockDim.x + threadIdx.x;
  long long stride = (long long)gridDim.x * blockDim.x;
  float sum = 0.f;
  for (long long i = g; i < total; i += stride) {
    int j = (int)(i >> 7);
    int f = (int)(i & 127);
    int v = midx[j];
    float d = r[i] - x[(size_t)v * 128 + f];
    sum += d * d;
  }
  for (int off = 32; off; off >>= 1) sum += __shfl_down(sum, off);
  __shared__ float sb[4];
  int wid = threadIdx.x >> 6;
  if ((threadIdx.x & 63) == 0) sb[wid] = sum;
  __syncthreads();
  if (threadIdx.x == 0) {
    float t = 0.f;
    for (int w = 0; w < (int)blockDim.x / 64; ++w) t += sb[w];
    atomicAdd(accum, t);
  }
}

__global__ void finalize_kernel(const float* accum, const int* cnt, float* out) {
  float denom = fmaxf((float)*cnt, 1.0f) * 128.0f;
  out[0] = *accum / denom;
}

// ---------------- launch ----------------
extern "C" void kernel_launch(void* const* d_in, const int* in_sizes, int n_in,
                              void* d_out, int out_size, void* d_ws, size_t ws_size,
                              hipStream_t stream) {
  const float* x  = (const float*)d_in[0];
  const void* edge = d_in[1];
  const void* mask = d_in[2];
  const float* W1 = (const float*)d_in[3];
  const float* b1 = (const float*)d_in[4];
  const float* W2 = (const float*)d_in[5];
  const float* b2 = (const float*)d_in[6];
  const float* W3 = (const float*)d_in[7];
  const float* b3 = (const float*)d_in[8];
  const float* D1 = (const float*)d_in[9];
  const float* db1 = (const float*)d_in[10];
  const float* D2 = (const float*)d_in[11];
  const float* db2 = (const float*)d_in[12];
  const float* D3 = (const float*)d_in[13];
  const float* db3 = (const float*)d_in[14];

  int N = in_sizes[0] / DD;
  long long E = in_sizes[1] / 2;
  long long Npad = ((long long)N + 63) & ~63LL;

  char* ws = (char*)d_ws;
  size_t p = 0;
  auto alloc = [&](size_t bytes) {
    size_t o = p;
    p = (p + bytes + 255) & ~(size_t)255;
    return o;
  };
  int* flags   = (int*)(ws + alloc(8));
  float* accum = (float*)(ws + alloc(4));
  int* mcnt    = (int*)(ws + alloc(4));
  int* qnext   = (int*)(ws + alloc(sizeof(int) * 8));
  int* deg     = (int*)(ws + alloc(sizeof(int) * N));
  float* dinv  = (float*)(ws + alloc(sizeof(float) * Npad));
  int* row_ptr = (int*)(ws + alloc(sizeof(int) * (N + 1)));
  int* cursor  = (int*)(ws + alloc(sizeof(int) * N));
  int* bsums   = (int*)(ws + alloc(sizeof(int) * 1024));
  int* midx    = (int*)(ws + alloc(sizeof(int) * N));
  int* s32     = (int*)(ws + alloc(sizeof(int) * E));
  int* d32     = (int*)(ws + alloc(sizeof(int) * E));
  int* csr     = (int*)(ws + alloc(sizeof(int) * (E + 16)));
  ushort_t* wt = (ushort_t*)(ws + alloc(sizeof(ushort_t) * 6 * 128 * 128));
  // union region: xb (bf16, matmul1 only) overlaps fb (f32 decoder out)
  char* uni    = ws + alloc(sizeof(float) * (size_t)Npad * DD);
  ushort_t* xb = (ushort_t*)uni;
  float* fb    = (float*)uni;
  ushort_t* hb = (ushort_t*)(ws + alloc(sizeof(ushort_t) * (size_t)Npad * DD));
  ushort_t* gb = (ushort_t*)(ws + alloc(sizeof(ushort_t) * (size_t)Npad * DD));

  hipMemsetAsync(deg, 0, sizeof(int) * N, stream);
  hipMemsetAsync(accum, 0, 4, stream);
  hipMemsetAsync(mcnt, 0, 4, stream);
  hipMemsetAsync(qnext, 0, sizeof(int) * 8, stream);

  // graph prep
  detect_kernel<<<1, 256, 0, stream>>>(edge, mask, E, N, flags);
  cvt_kernel<<<1024, 256, 0, stream>>>(edge, E, s32, d32, deg, flags);
  dinv_kernel<<<(int)((Npad + 255) / 256), 256, 0, stream>>>(deg, dinv, N, (int)Npad);
  int nb = (N + 1023) / 1024;
  scan1_kernel<<<nb, 1024, 0, stream>>>(deg, row_ptr, bsums, N);
  scan2_kernel<<<1, 1, 0, stream>>>(bsums, nb, row_ptr, N);
  scan3_kernel<<<nb, 1024, 0, stream>>>(row_ptr, bsums, cursor, N);
  fillx_kernel<<<1024, 256, 0, stream>>>(s32, d32, E, cursor, csr, N, qnext);
  compact_kernel<<<(N + 255) / 256, 256, 0, stream>>>(mask, flags, N, mcnt, midx);

  // cast + weight prep
  long long ntotal = Npad * DD;
  castx_kernel<<<(int)((ntotal / 8 + 255) / 256), 256, 0, stream>>>(x, xb, (long long)N * DD, ntotal);
  WPtrs wp;
  wp.w[0] = W1; wp.w[1] = W2; wp.w[2] = W3;
  wp.w[3] = D1; wp.w[4] = D2; wp.w[5] = D3;
  transw_kernel<<<6, 256, 0, stream>>>(wp, wt);

  float* zout = (float*)d_out + 1;
  int mmb = (int)(Npad / 64);
  int aggb = (N + 3) / 4;

  // encoder (mm stores ht = dinv * (A@W) in bf16)
  mm_kernel<<<mmb, 256, 0, stream>>>(xb, wt + 0 * 16384, nullptr, hb, nullptr, 0,
                                     (int)Npad, nullptr, nullptr, dinv);
  agg_kernel<<<aggb, 256, 0, stream>>>(hb, dinv, row_ptr, csr, b1, gb, nullptr, N);
  mm_kernel<<<mmb, 256, 0, stream>>>(gb, wt + 1 * 16384, nullptr, hb, nullptr, 0,
                                     (int)Npad, nullptr, nullptr, dinv);
  agg_kernel<<<aggb, 256, 0, stream>>>(hb, dinv, row_ptr, csr, b2, gb, nullptr, N);
  mm_kernel<<<mmb, 256, 0, stream>>>(gb, wt + 2 * 16384, nullptr, hb, nullptr, 0,
                                     (int)Npad, nullptr, nullptr, dinv);
  agg_kernel<<<aggb, 256, 0, stream>>>(hb, dinv, row_ptr, csr, b3, gb, zout, N);

  // decoder on compact masked rows (d1 gathers z rows via midx)
  mm_kernel<<<mmb, 256, 0, stream>>>(gb, wt + 3 * 16384, db1, hb, nullptr, 1,
                                     (int)Npad, midx, mcnt, nullptr);
  mm_kernel<<<mmb, 256, 0, stream>>>(hb, wt + 4 * 16384, db2, gb, nullptr, 1,
                                     (int)Npad, nullptr, mcnt, nullptr);
  mm_kernel<<<mmb, 256, 0, stream>>>(gb, wt + 5 * 16384, db3, nullptr, fb, 0,
                                     (int)Npad, nullptr, mcnt, nullptr);

  // loss
  loss_kernel<<<1024, 256, 0, stream>>>(fb, x, midx, mcnt, accum);
  finalize_kernel<<<1, 1, 0, stream>>>(accum, mcnt, (float*)d_out);
}

// Round 8
// 559.902 us; speedup vs baseline: 1.2015x; 1.2015x over previous
//
#include <hip/hip_runtime.h>
#include <hip/hip_bf16.h>
#include <math.h>

// GraphMAE: 3x GCNConv(relu) encoder -> 3-layer MLP decoder -> masked MSE.
// bf16 activation storage, f32 compute, MFMA bf16 matmuls.
// Round 8: fillx reverted to fillp (wider grid). agg 8-deep gather MLP.
// castx fused into mm1 (f32 input path). loss fused into decoder mm3.
// Outputs: d_out[0] = loss, d_out[1..N*128] = z (f32).

#define DD 128

typedef unsigned short ushort_t;
typedef unsigned int uint_t;
typedef __attribute__((ext_vector_type(8))) short short8;
typedef __attribute__((ext_vector_type(4))) float f32x4;

__device__ __forceinline__ ushort_t f2bf(float f) {
  union { float f; uint_t u; } v; v.f = f;
  uint_t r = v.u + 0x7fff + ((v.u >> 16) & 1);
  return (ushort_t)(r >> 16);
}
__device__ __forceinline__ float u2f(uint_t u) {
  union { uint_t u; float f; } v; v.u = u;
  return v.f;
}

// ---------------- dtype detection (edge_index: i64 vs i32; mask: i32 vs u8) ---
__global__ void detect_kernel(const void* edge, const void* mask,
                              long long E, int N, int* flags) {
  __shared__ int bad_e, bad_m;
  if (threadIdx.x == 0) { bad_e = 0; bad_m = 0; }
  __syncthreads();
  const long long* e64 = (const long long*)edge;
  long long step = E / 1024; if (step < 1) step = 1;
  for (int i = threadIdx.x; i < 1024; i += blockDim.x) {
    long long idx = (long long)i * step;
    if (idx < E) {
      long long v = e64[idx];
      if (v < 0 || v >= N) atomicAdd(&bad_e, 1);
    }
  }
  const int* m32 = (const int*)mask;
  int nw = N / 4;
  for (int i = threadIdx.x; i < nw; i += blockDim.x) {
    int v = m32[i];
    if (v != 0 && v != 1) atomicAdd(&bad_m, 1);
  }
  __syncthreads();
  if (threadIdx.x == 0) {
    flags[0] = (bad_e == 0) ? 1 : 0;
    flags[1] = (bad_m == 0) ? 1 : 0;
  }
}

__device__ __forceinline__ int load_mask(const void* p, int i, int is32) {
  if (is32) return ((const int*)p)[i];
  return (int)((const unsigned char*)p)[i];
}

// ---------------- edge convert to int32 + degree count (fused) --------------
__global__ void cvt_kernel(const void* edge, long long E, int* s32, int* d32,
                           int* deg, const int* flags) {
  int is64 = flags[0];
  long long i = blockIdx.x * (long long)blockDim.x + threadIdx.x;
  long long stride = (long long)gridDim.x * blockDim.x;
  for (; i < E; i += stride) {
    int s, d;
    if (is64) {
      s = (int)((const long long*)edge)[i];
      d = (int)((const long long*)edge)[E + i];
    } else {
      s = ((const int*)edge)[i];
      d = ((const int*)edge)[E + i];
    }
    s32[i] = s;
    d32[i] = d;
    atomicAdd(&deg[d], 1);
  }
}

__global__ void dinv_kernel(const int* deg, float* dinv, int N, int Npad) {
  int i = blockIdx.x * blockDim.x + threadIdx.x;
  if (i < Npad) dinv[i] = (i < N) ? rsqrtf((float)deg[i] + 1.0f) : 0.f;
}

// ---------------- exclusive scan (3-pass) ----------------
__global__ void scan1_kernel(const int* cnt, int* row_excl, int* blocksums, int N) {
  __shared__ int s[1024];
  int t = threadIdx.x, g = blockIdx.x * 1024 + t;
  int v = (g < N) ? cnt[g] : 0;
  s[t] = v;
  __syncthreads();
  for (int off = 1; off < 1024; off <<= 1) {
    int add = (t >= off) ? s[t - off] : 0;
    __syncthreads();
    s[t] += add;
    __syncthreads();
  }
  if (g < N) row_excl[g] = s[t] - v;
  if (t == 1023) blocksums[blockIdx.x] = s[1023];
}

__global__ void scan2_kernel(int* blocksums, int nb, int* row_ptr, int N) {
  if (threadIdx.x == 0 && blockIdx.x == 0) {
    int run = 0;
    for (int b = 0; b < nb; ++b) { int t = blocksums[b]; blocksums[b] = run; run += t; }
    row_ptr[N] = run;
  }
}

__global__ void scan3_kernel(int* row_ptr, const int* blocksums, int* cursor, int N) {
  int g = blockIdx.x * 1024 + threadIdx.x;
  if (g < N) {
    int v = row_ptr[g] + blocksums[blockIdx.x];
    row_ptr[g] = v;
    cursor[g] = v;
  }
}

// ---------------- CSR fill, partitioned by dst range, int32 streams ---------
__global__ void fillp_kernel(const int* __restrict__ s32, const int* __restrict__ d32,
                             long long E, int* cursor, int* csr_src, int N) {
  int part = blockIdx.x & 7;
  int lo = (int)(((long long)N * part) >> 3);
  int hi = (int)(((long long)N * (part + 1)) >> 3);
  long long i = (long long)(blockIdx.x >> 3) * blockDim.x + threadIdx.x;
  long long stride = (long long)(gridDim.x >> 3) * blockDim.x;
  for (; i < E; i += stride) {
    int d = d32[i];
    if (d >= lo && d < hi) {
      int s = s32[i];
      int pos = atomicAdd(&cursor[d], 1);
      csr_src[pos] = s;
    }
  }
}

// ---------------- transpose+cast weights: W[k][n] f32 -> WT[n][k] bf16 ------
struct WPtrs { const float* w[6]; };
__global__ void transw_kernel(WPtrs p, ushort_t* wt) {
  int wi = blockIdx.x;
  const float* W = p.w[wi];
  ushort_t* dst = wt + wi * 16384;
  for (int i = threadIdx.x; i < 16384; i += blockDim.x) {
    int k = i >> 7, n = i & 127;
    dst[n * 128 + k] = f2bf(W[i]);
  }
}

// ---------------- mask compaction (order-free) ----------------
__global__ void compact_kernel(const void* mask, const int* flags, int N,
                               int* cnt, int* midx) {
  int i = blockIdx.x * blockDim.x + threadIdx.x;
  if (i < N && load_mask(mask, i, flags[1])) {
    int p = atomicAdd(cnt, 1);
    midx[p] = i;
  }
}

// ---------------- MFMA matmul: out[rows][128] = A[rows][128] @ W ------------
// A bf16 row-major OR f32 (Af32 path, converted in-register; rows >= nvalid
// read as zero). WT bf16 [n][k] pre-transposed, LDS-staged w/ XOR swizzle.
// gidx: logical row r reads A row gidx[r]. gM: device row limit (compact).
// scale: per-row output multiplier (dinv premult). xloss/lidx/accum: fused
// masked-MSE epilogue (no stores; block-reduced atomicAdd of sq-diff).
__launch_bounds__(256, 4)
__global__ void mm_kernel(const ushort_t* __restrict__ A, const float* __restrict__ Af32,
                          int nvalid, const ushort_t* __restrict__ WT,
                          const float* __restrict__ bias, ushort_t* __restrict__ outb,
                          float* __restrict__ outf, int do_relu, int nrows,
                          const int* __restrict__ gidx, const int* __restrict__ gM,
                          const float* __restrict__ scale,
                          const float* __restrict__ xloss, const int* __restrict__ lidx,
                          float* __restrict__ accum) {
  int limit = nrows;
  if (gM) limit = *gM;
  if ((long long)blockIdx.x * 64 >= limit) return;

  __shared__ __align__(16) char lds[32768];
  int tid = threadIdx.x;
  for (int cid = tid; cid < 2048; cid += 256) {
    int n = cid >> 4, kc = cid & 15;
    int dst = n * 256 + ((kc * 16) ^ ((n & 7) << 4));
    *(float4*)(lds + dst) = *(const float4*)(WT + n * 128 + kc * 8);
  }
  __syncthreads();

  int w = tid >> 6, l = tid & 63;
  long long R0 = (long long)blockIdx.x * 64 + w * 16;
  f32x4 acc[8];
#pragma unroll
  for (int c = 0; c < 8; ++c) acc[c] = (f32x4){0.f, 0.f, 0.f, 0.f};

  int r_log = (int)R0 + (l & 15);
  long long r_phys = r_log;
  if (gidx) r_phys = (r_log < limit) ? (long long)gidx[r_log] : 0;
#pragma unroll
  for (int ks = 0; ks < 4; ++ks) {
    short8 a;
    if (Af32) {
      if (r_log < nvalid) {
        const float* ar = Af32 + r_phys * 128 + ks * 32 + ((l >> 4) << 3);
        float4 f0 = *(const float4*)ar;
        float4 f1 = *(const float4*)(ar + 4);
        a[0] = (short)f2bf(f0.x); a[1] = (short)f2bf(f0.y);
        a[2] = (short)f2bf(f0.z); a[3] = (short)f2bf(f0.w);
        a[4] = (short)f2bf(f1.x); a[5] = (short)f2bf(f1.y);
        a[6] = (short)f2bf(f1.z); a[7] = (short)f2bf(f1.w);
      } else {
#pragma unroll
        for (int j = 0; j < 8; ++j) a[j] = 0;
      }
    } else {
      a = *(const short8*)(A + r_phys * 128 + ks * 32 + ((l >> 4) << 3));
    }
#pragma unroll
    for (int c = 0; c < 8; ++c) {
      int nn = c * 16 + (l & 15);
      int kb = ks * 64 + ((l >> 4) << 4);
      short8 b = *(const short8*)(lds + nn * 256 + (kb ^ ((nn & 7) << 4)));
      acc[c] = __builtin_amdgcn_mfma_f32_16x16x32_bf16(a, b, acc[c], 0, 0, 0);
    }
  }

  int store_limit = gM ? limit : nrows;
  long long gr0 = R0 + ((l >> 4) << 2);
  float sc[4] = {1.f, 1.f, 1.f, 1.f};
  if (scale) {
#pragma unroll
    for (int r = 0; r < 4; ++r)
      sc[r] = (gr0 + r < store_limit) ? scale[gr0 + r] : 0.f;
  }
  float local_sq = 0.f;
#pragma unroll
  for (int c = 0; c < 8; ++c) {
    int col = c * 16 + (l & 15);
    float bia = bias ? bias[col] : 0.f;
#pragma unroll
    for (int r = 0; r < 4; ++r) {
      if (gr0 + r < store_limit) {
        float v = acc[c][r] * sc[r] + bia;
        if (do_relu) v = fmaxf(v, 0.f);
        long long idx = (gr0 + r) * 128 + col;
        if (outb) outb[idx] = f2bf(v);
        if (outf) outf[idx] = v;
        if (xloss) {
          int orow = lidx[gr0 + r];
          float d = v - xloss[(size_t)orow * 128 + col];
          local_sq += d * d;
        }
      }
    }
  }
  if (accum) {
    float s = local_sq;
    for (int off2 = 32; off2; off2 >>= 1) s += __shfl_down(s, off2);
    __syncthreads();
    float* red = (float*)lds;
    if (l == 0) red[w] = s;
    __syncthreads();
    if (tid == 0) atomicAdd(accum, red[0] + red[1] + red[2] + red[3]);
  }
}

// ---------------- GCN aggregation (wave/node; ht rows dinv-premultiplied) ----
// out[v] = relu(dv*(sum_{edges} ht[s] + ht[v]) + b); 8 gathers in flight.
__global__ void agg_kernel(const ushort_t* __restrict__ ht, const float* __restrict__ dinv,
                           const int* __restrict__ rp, const int* __restrict__ csr,
                           const float* __restrict__ bias, ushort_t* __restrict__ outb,
                           float* __restrict__ zout, int N) {
  int v = blockIdx.x * 4 + (threadIdx.x >> 6);
  if (v >= N) return;
  int l = threadIdx.x & 63;
  int off = l * 2;
  int e0 = rp[v], e1 = rp[v + 1];

  float ax[8], ay[8];
#pragma unroll
  for (int j = 0; j < 8; ++j) { ax[j] = 0.f; ay[j] = 0.f; }

  for (int e = e0; e < e1; e += 8) {
    int last = e1 - 1;
#pragma unroll
    for (int j = 0; j < 8; ++j) {
      int idx = e + j;
      bool act = idx < e1;
      idx = act ? idx : last;
      int s = csr[idx];
      uint_t hv = *(const uint_t*)(ht + (size_t)s * 128 + off);
      hv = act ? hv : 0u;
      ax[j] += u2f(hv << 16);
      ay[j] += u2f(hv & 0xffff0000u);
    }
  }

  float dv = dinv[v];
  uint_t sv = *(const uint_t*)(ht + (size_t)v * 128 + off);
  float axs = ((ax[0] + ax[1]) + (ax[2] + ax[3])) + ((ax[4] + ax[5]) + (ax[6] + ax[7]));
  float ays = ((ay[0] + ay[1]) + (ay[2] + ay[3])) + ((ay[4] + ay[5]) + (ay[6] + ay[7]));
  axs += u2f(sv << 16);
  ays += u2f(sv & 0xffff0000u);
  float vx = fmaxf(dv * axs + bias[off], 0.f);
  float vy = fmaxf(dv * ays + bias[off + 1], 0.f);
  uint_t packed = (uint_t)f2bf(vx) | ((uint_t)f2bf(vy) << 16);
  *(uint_t*)(outb + (size_t)v * 128 + off) = packed;
  if (zout) {
    *(float2*)(zout + (size_t)v * 128 + off) = make_float2(vx, vy);
  }
}

__global__ void finalize_kernel(const float* accum, const int* cnt, float* out) {
  float denom = fmaxf((float)*cnt, 1.0f) * 128.0f;
  out[0] = *accum / denom;
}

// ---------------- launch ----------------
extern "C" void kernel_launch(void* const* d_in, const int* in_sizes, int n_in,
                              void* d_out, int out_size, void* d_ws, size_t ws_size,
                              hipStream_t stream) {
  const float* x  = (const float*)d_in[0];
  const void* edge = d_in[1];
  const void* mask = d_in[2];
  const float* W1 = (const float*)d_in[3];
  const float* b1 = (const float*)d_in[4];
  const float* W2 = (const float*)d_in[5];
  const float* b2 = (const float*)d_in[6];
  const float* W3 = (const float*)d_in[7];
  const float* b3 = (const float*)d_in[8];
  const float* D1 = (const float*)d_in[9];
  const float* db1 = (const float*)d_in[10];
  const float* D2 = (const float*)d_in[11];
  const float* db2 = (const float*)d_in[12];
  const float* D3 = (const float*)d_in[13];
  const float* db3 = (const float*)d_in[14];

  int N = in_sizes[0] / DD;
  long long E = in_sizes[1] / 2;
  long long Npad = ((long long)N + 63) & ~63LL;

  char* ws = (char*)d_ws;
  size_t p = 0;
  auto alloc = [&](size_t bytes) {
    size_t o = p;
    p = (p + bytes + 255) & ~(size_t)255;
    return o;
  };
  int* flags   = (int*)(ws + alloc(8));
  float* accum = (float*)(ws + alloc(4));
  int* mcnt    = (int*)(ws + alloc(4));
  int* deg     = (int*)(ws + alloc(sizeof(int) * N));
  float* dinv  = (float*)(ws + alloc(sizeof(float) * Npad));
  int* row_ptr = (int*)(ws + alloc(sizeof(int) * (N + 1)));
  int* cursor  = (int*)(ws + alloc(sizeof(int) * N));
  int* bsums   = (int*)(ws + alloc(sizeof(int) * 1024));
  int* midx    = (int*)(ws + alloc(sizeof(int) * N));
  int* s32     = (int*)(ws + alloc(sizeof(int) * E));
  int* d32     = (int*)(ws + alloc(sizeof(int) * E));
  int* csr     = (int*)(ws + alloc(sizeof(int) * (E + 16)));
  ushort_t* wt = (ushort_t*)(ws + alloc(sizeof(ushort_t) * 6 * 128 * 128));
  ushort_t* hb = (ushort_t*)(ws + alloc(sizeof(ushort_t) * (size_t)Npad * DD));
  ushort_t* gb = (ushort_t*)(ws + alloc(sizeof(ushort_t) * (size_t)Npad * DD));

  hipMemsetAsync(deg, 0, sizeof(int) * N, stream);
  hipMemsetAsync(accum, 0, 4, stream);
  hipMemsetAsync(mcnt, 0, 4, stream);

  // graph prep
  detect_kernel<<<1, 256, 0, stream>>>(edge, mask, E, N, flags);
  cvt_kernel<<<1024, 256, 0, stream>>>(edge, E, s32, d32, deg, flags);
  dinv_kernel<<<(int)((Npad + 255) / 256), 256, 0, stream>>>(deg, dinv, N, (int)Npad);
  int nb = (N + 1023) / 1024;
  scan1_kernel<<<nb, 1024, 0, stream>>>(deg, row_ptr, bsums, N);
  scan2_kernel<<<1, 1, 0, stream>>>(bsums, nb, row_ptr, N);
  scan3_kernel<<<nb, 1024, 0, stream>>>(row_ptr, bsums, cursor, N);
  fillp_kernel<<<4096, 256, 0, stream>>>(s32, d32, E, cursor, csr, N);
  compact_kernel<<<(N + 255) / 256, 256, 0, stream>>>(mask, flags, N, mcnt, midx);

  // weight prep
  WPtrs wp;
  wp.w[0] = W1; wp.w[1] = W2; wp.w[2] = W3;
  wp.w[3] = D1; wp.w[4] = D2; wp.w[5] = D3;
  transw_kernel<<<6, 256, 0, stream>>>(wp, wt);

  float* zout = (float*)d_out + 1;
  int mmb = (int)(Npad / 64);
  int aggb = (N + 3) / 4;

  // encoder (mm stores ht = dinv * (A@W) in bf16; mm1 reads f32 x directly)
  mm_kernel<<<mmb, 256, 0, stream>>>(nullptr, x, N, wt + 0 * 16384, nullptr, hb,
                                     nullptr, 0, (int)Npad, nullptr, nullptr, dinv,
                                     nullptr, nullptr, nullptr);
  agg_kernel<<<aggb, 256, 0, stream>>>(hb, dinv, row_ptr, csr, b1, gb, nullptr, N);
  mm_kernel<<<mmb, 256, 0, stream>>>(gb, nullptr, 0, wt + 1 * 16384, nullptr, hb,
                                     nullptr, 0, (int)Npad, nullptr, nullptr, dinv,
                                     nullptr, nullptr, nullptr);
  agg_kernel<<<aggb, 256, 0, stream>>>(hb, dinv, row_ptr, csr, b2, gb, nullptr, N);
  mm_kernel<<<mmb, 256, 0, stream>>>(gb, nullptr, 0, wt + 2 * 16384, nullptr, hb,
                                     nullptr, 0, (int)Npad, nullptr, nullptr, dinv,
                                     nullptr, nullptr, nullptr);
  agg_kernel<<<aggb, 256, 0, stream>>>(hb, dinv, row_ptr, csr, b3, gb, zout, N);

  // decoder on compact masked rows (d1 gathers z rows via midx; d3 fuses loss)
  mm_kernel<<<mmb, 256, 0, stream>>>(gb, nullptr, 0, wt + 3 * 16384, db1, hb,
                                     nullptr, 1, (int)Npad, midx, mcnt, nullptr,
                                     nullptr, nullptr, nullptr);
  mm_kernel<<<mmb, 256, 0, stream>>>(hb, nullptr, 0, wt + 4 * 16384, db2, gb,
                                     nullptr, 1, (int)Npad, nullptr, mcnt, nullptr,
                                     nullptr, nullptr, nullptr);
  mm_kernel<<<mmb, 256, 0, stream>>>(gb, nullptr, 0, wt + 5 * 16384, db3, nullptr,
                                     nullptr, 0, (int)Npad, nullptr, mcnt, nullptr,
                                     x, midx, accum);

  finalize_kernel<<<1, 1, 0, stream>>>(accum, mcnt, (float*)d_out);
}